// Round 17
// baseline (209.413 us; speedup 1.0000x reference)
//
#include <hip/hip_runtime.h>

typedef unsigned short u16;
typedef unsigned int u32;
typedef __attribute__((ext_vector_type(8))) __bf16 bf16x8;
typedef __attribute__((ext_vector_type(4))) float f32x4;

#define MFMA(a, b, c) __builtin_amdgcn_mfma_f32_16x16x32_bf16((a), (b), (c), 0, 0, 0)

__device__ __forceinline__ u16 f2bf(float f) {
  union { float f; unsigned u; } v; v.f = f;
  unsigned r = v.u + 0x7fffu + ((v.u >> 16) & 1u);
  return (u16)(r >> 16);
}

// async global->LDS, 16B per lane; LDS dest must be linear (base + lane*16)
__device__ __forceinline__ void gld16(const u16* g, u16* l) {
  __builtin_amdgcn_global_load_lds(
      (const __attribute__((address_space(1))) unsigned int*)(g),
      (__attribute__((address_space(3))) unsigned int*)(l), 16, 0, 0);
}

// ---------------- cast + prescale kernel ----------------
// dst layout (bf16 elems): [query 4M][wq/8 1M][wk 1M][wv 1M][wo 1M]
__global__ __launch_bounds__(256) void k_cast(
    const float* __restrict__ query, const float* __restrict__ wq,
    const float* __restrict__ wk, const float* __restrict__ wv,
    const float* __restrict__ wo, u16* __restrict__ dst)
{
  size_t i = ((size_t)blockIdx.x * 256 + threadIdx.x) * 8;
  const float* src; size_t off; float sc = 1.0f;
  if (i < 4194304u)      { src = query; off = i; }
  else if (i < 5242880u) { src = wq; off = i - 4194304u; sc = 0.125f; }
  else if (i < 6291456u) { src = wk; off = i - 5242880u; }
  else if (i < 7340032u) { src = wv; off = i - 6291456u; }
  else                   { src = wo; off = i - 7340032u; }
  float4 a = *(const float4*)(src + off);
  float4 b = *(const float4*)(src + off + 4);
  alignas(16) u16 r[8] = { f2bf(a.x*sc), f2bf(a.y*sc), f2bf(a.z*sc), f2bf(a.w*sc),
                           f2bf(b.x*sc), f2bf(b.y*sc), f2bf(b.z*sc), f2bf(b.w*sc) };
  *(int4*)(dst + i) = *(int4*)r;
}

// ---------------- QKV GEMM: [4096,1024] x [3072,1024]^T ----------------
// 128x128 tile, 4 waves (2x2). grid 768 = 24 n-tiles x 32 m-tiles, XCD-chunked.
// V panel written DIRECTLY transposed Vt[bh][64][2048]; jj-quads packed into
// single uint2 (8B) stores (4 consecutive n at fixed d64 are thread-local).
__global__ __launch_bounds__(256) void k_gemm_qkv(
    const u16* __restrict__ Ab, const u16* __restrict__ Wb,
    const float* __restrict__ bq, const float* __restrict__ bk, const float* __restrict__ bv,
    u16* __restrict__ Qh, u16* __restrict__ Kh, u16* __restrict__ Vt)
{
  const int fb = blockIdx.x;
  const int sb = (fb & 7) * 96 + (fb >> 3);     // 768/8 = 96 per XCD
  const int n0 = (sb % 24) * 128;
  const int m0 = (sb / 24) * 128;
  const int tid = threadIdx.x;
  const int w = tid >> 6, lane = tid & 63, g = lane >> 4, l15 = lane & 15;
  const int wm = w >> 1, wn = w & 1;
  __shared__ alignas(16) u16 As[128 * 32];
  __shared__ alignas(16) u16 Bs[128 * 32];
  f32x4 acc[4][4] = {};
  for (int k0 = 0; k0 < 1024; k0 += 32) {
    __syncthreads();
#pragma unroll
    for (int t = 0; t < 2; ++t) {
      int i = t * 256 + tid;
      int row = i >> 2, ch = i & 3, sch = ch ^ (row & 3);
      gld16(Ab + (size_t)(m0 + row) * 1024 + k0 + sch * 8, As + i * 8);
    }
#pragma unroll
    for (int t = 0; t < 2; ++t) {
      int i = t * 256 + tid;
      int row = i >> 2, ch = i & 3, sch = ch ^ (row & 3);
      gld16(Wb + (size_t)(n0 + row) * 1024 + k0 + sch * 8, Bs + i * 8);
    }
    __syncthreads();
    bf16x8 af[4], bfr[4];
#pragma unroll
    for (int i = 0; i < 4; ++i) {
      int row = wm * 64 + i * 16 + l15;
      af[i] = *(const bf16x8*)(As + (row * 4 + (g ^ (row & 3))) * 8);
    }
#pragma unroll
    for (int j = 0; j < 4; ++j) {
      int row = wn * 64 + j * 16 + l15;
      bfr[j] = *(const bf16x8*)(Bs + (row * 4 + (g ^ (row & 3))) * 8);
    }
#pragma unroll
    for (int i = 0; i < 4; ++i)
#pragma unroll
      for (int j = 0; j < 4; ++j)
        acc[i][j] = MFMA(af[i], bfr[j], acc[i][j]);
  }
  // epilogue: Q/K -> [bh][n][64] (scalar); V -> Vt[bh][64][2048] (uint2-packed)
  const int proj = n0 >> 10;                    // block-uniform (128 | 1024)
  if (proj == 2) {
#pragma unroll
    for (int i = 0; i < 4; ++i)
#pragma unroll
      for (int j = 0; j < 4; ++j) {
        int c = n0 + wn * 64 + j * 16 + l15;
        int d = c & 1023, h = d >> 6, d64 = d & 63;
        int mr0 = m0 + wm * 64 + i * 16 + g * 4;
        int b = mr0 >> 11, n = mr0 & 2047;
        float bvv = bv[d];
        alignas(8) u16 q4[4];
#pragma unroll
        for (int jj = 0; jj < 4; ++jj) q4[jj] = f2bf(acc[i][j][jj] + bvv);
        *(uint2*)(Vt + ((size_t)(((b << 4) | h) * 64 + d64)) * 2048 + n) = *(uint2*)q4;
      }
  } else {
    const float* bias = (proj == 0) ? bq : bk;
    const float bsc = (proj == 0) ? 0.125f : 1.0f;
    u16* dst = (proj == 0) ? Qh : Kh;
#pragma unroll
    for (int i = 0; i < 4; ++i)
#pragma unroll
      for (int j = 0; j < 4; ++j)
#pragma unroll
        for (int jj = 0; jj < 4; ++jj) {
          int mr = m0 + wm * 64 + i * 16 + g * 4 + jj;
          int c  = n0 + wn * 64 + j * 16 + l15;
          int d = c & 1023, h = d >> 6, d64 = d & 63;
          int b = mr >> 11, n = mr & 2047;
          float v = acc[i][j][jj] + bias[d] * bsc;
          dst[((size_t)(((b << 4) | h) * 2048 + n)) * 64 + d64] = f2bf(v);
        }
  }
}

// ---------------- out projection: ctx[4096,1024] x Wo[1024,1024]^T + bo ----------------
// grid 256 = 8 n-tiles x 32 m-tiles, XCD-chunked.
__global__ __launch_bounds__(256) void k_gemm_out(
    const u16* __restrict__ Ab, const u16* __restrict__ Wb,
    const float* __restrict__ bo, float* __restrict__ out)
{
  const int fb = blockIdx.x;
  const int sb = (fb & 7) * 32 + (fb >> 3);     // 256/8 = 32 per XCD
  const int n0 = (sb & 7) * 128;
  const int m0 = (sb >> 3) * 128;
  const int tid = threadIdx.x;
  const int w = tid >> 6, lane = tid & 63, g = lane >> 4, l15 = lane & 15;
  const int wm = w >> 1, wn = w & 1;
  __shared__ alignas(16) u16 As[128 * 32];
  __shared__ alignas(16) u16 Bs[128 * 32];
  f32x4 acc[4][4] = {};
  for (int k0 = 0; k0 < 1024; k0 += 32) {
    __syncthreads();
#pragma unroll
    for (int t = 0; t < 2; ++t) {
      int i = t * 256 + tid;
      int row = i >> 2, ch = i & 3, sch = ch ^ (row & 3);
      gld16(Ab + (size_t)(m0 + row) * 1024 + k0 + sch * 8, As + i * 8);
    }
#pragma unroll
    for (int t = 0; t < 2; ++t) {
      int i = t * 256 + tid;
      int row = i >> 2, ch = i & 3, sch = ch ^ (row & 3);
      gld16(Wb + (size_t)(n0 + row) * 1024 + k0 + sch * 8, Bs + i * 8);
    }
    __syncthreads();
    bf16x8 af[4], bfr[4];
#pragma unroll
    for (int i = 0; i < 4; ++i) {
      int row = wm * 64 + i * 16 + l15;
      af[i] = *(const bf16x8*)(As + (row * 4 + (g ^ (row & 3))) * 8);
    }
#pragma unroll
    for (int j = 0; j < 4; ++j) {
      int row = wn * 64 + j * 16 + l15;
      bfr[j] = *(const bf16x8*)(Bs + (row * 4 + (g ^ (row & 3))) * 8);
    }
#pragma unroll
    for (int i = 0; i < 4; ++i)
#pragma unroll
      for (int j = 0; j < 4; ++j)
        acc[i][j] = MFMA(af[i], bfr[j], acc[i][j]);
  }
#pragma unroll
  for (int i = 0; i < 4; ++i)
#pragma unroll
    for (int j = 0; j < 4; ++j)
#pragma unroll
      for (int jj = 0; jj < 4; ++jj) {
        int mr = m0 + wm * 64 + i * 16 + g * 4 + jj;
        int c  = n0 + wn * 64 + j * 16 + l15;
        out[(size_t)mr * 1024 + c] = acc[i][j][jj] + bo[c];
      }
}

// ---------------- fused flash attention + dot_prod write ----------------
// grid 1024 = 32 qtiles x 32 bh, XCD-chunked; block 256 = 4 waves.
// R15 (best, 200.8us): K double-buffered, V single-buffered JIT, two COUNTED
// barriers/iter (A: vmcnt(40) retires K; B: vmcnt(44) retires V); NT S-stores
// never drained. LDS 53.0 KB -> 3 blocks/CU.
__global__ __launch_bounds__(256) void k_attn(
    const u16* __restrict__ Qh, const u16* __restrict__ Kh, const u16* __restrict__ Vt,
    const int* __restrict__ mask, float* __restrict__ dout, u16* __restrict__ ctx)
{
  const int fb = blockIdx.x;
  const int sb = (fb & 7) * 128 + (fb >> 3);    // 1024/8 = 128 per XCD
  const int qt = sb & 31;
  const int bh = sb >> 5;
  const int b  = bh >> 4;
  const int tid = threadIdx.x;
  const int w = tid >> 6, lane = tid & 63, g = lane >> 4, l15 = lane & 15;
  __shared__ alignas(16) u16 Ks[2][128 * 64];   // 32 KB (double-buffered)
  __shared__ alignas(16) u16 Vs[64 * 128];      // 16 KB (single, JIT)
  __shared__ alignas(16) u16 Ps[4][16 * 40];    // 5 KB, per-wave [q=16][kv=32]

  // Q fragments straight from global (once per block; k-chunks g and 4+g)
  const u16* Qrow = Qh + ((size_t)bh * 2048 + qt * 64 + w * 16 + l15) * 64;
  bf16x8 qf0 = *(const bf16x8*)(Qrow + g * 8);
  bf16x8 qf1 = *(const bf16x8*)(Qrow + 32 + g * 8);

  const u16* Kb = Kh + (size_t)bh * 131072;   // [2048][64]
  const u16* Vb = Vt + (size_t)bh * 131072;   // [64][2048]

  auto stageK = [&](int buf, int kt) {        // 4 gld16 / lane
#pragma unroll
    for (int it = 0; it < 4; ++it) {
      int i = it * 256 + tid;
      int row = i >> 3, ch = i & 7, sch = ch ^ (row & 7);
      gld16(Kb + (size_t)(kt * 128 + row) * 64 + sch * 8, &Ks[buf][i * 8]);
    }
  };
  auto stageV = [&](int kt) {                 // 4 gld16 / lane
#pragma unroll
    for (int it = 0; it < 4; ++it) {
      int i = it * 256 + tid;
      int row = i >> 4, ch = i & 15, sch = ch ^ (row & 15);
      gld16(Vb + (size_t)row * 2048 + kt * 128 + sch * 8, &Vs[i * 8]);
    }
  };

  stageK(0, 0);
  asm volatile("s_waitcnt vmcnt(0)" ::: "memory");
  __builtin_amdgcn_s_barrier();
  __builtin_amdgcn_sched_barrier(0);

  float m[4] = {-3e38f, -3e38f, -3e38f, -3e38f};
  float l[4] = {0.f, 0.f, 0.f, 0.f};
  f32x4 O[4] = {};
  const int* maskb = mask + b * 2048;
  float* Sbase = dout + 4194304 + (size_t)bh * 4194304
               + (size_t)(qt * 64 + w * 16 + g * 4) * 2048 + l15;

  for (int kt = 0; kt < 16; ++kt) {
    const int cur = kt & 1;
    // ---- barrier A: all waves done PV(kt-1); retire K(kt); stores stay ----
    asm volatile("s_waitcnt vmcnt(40)" ::: "memory");
    __builtin_amdgcn_s_barrier();
    __builtin_amdgcn_sched_barrier(0);

    stageV(kt);                               // V just-in-time (oldest this iter)
    __builtin_amdgcn_sched_barrier(0);
    stageK(cur ^ 1, (kt + 1) & 15);           // K prefetch (wraps at kt=15)
    __builtin_amdgcn_sched_barrier(0);

    int mk[8];
#pragma unroll
    for (int f = 0; f < 8; ++f) mk[f] = maskb[kt * 128 + f * 16 + l15];

    // S = Q K^T  (wave's 16 q-rows x 128 kv)
    f32x4 s[8];
#pragma unroll
    for (int f = 0; f < 8; ++f) {
      int row = f * 16 + l15;
      bf16x8 kf0 = *(const bf16x8*)(&Ks[cur][(row * 8 + ((0 + g) ^ (row & 7))) * 8]);
      bf16x8 kf1 = *(const bf16x8*)(&Ks[cur][(row * 8 + ((4 + g) ^ (row & 7))) * 8]);
      f32x4 t = {};
      t = MFMA(qf0, kf0, t);
      t = MFMA(qf1, kf1, t);
      s[f] = t;
    }

    float fb8[8];
#pragma unroll
    for (int f = 0; f < 8; ++f) fb8[f] = (mk[f] != 0) ? 0.f : -1e20f;

    // biased S: NT store + unconditional max
    float mloc[4] = {-3e38f, -3e38f, -3e38f, -3e38f};
#pragma unroll
    for (int jj = 0; jj < 4; ++jj)
#pragma unroll
      for (int f = 0; f < 8; ++f) {
        float sv = s[f][jj] + fb8[f];
        s[f][jj] = sv;
        __builtin_nontemporal_store(sv, &Sbase[(size_t)jj * 2048 + kt * 128 + f * 16]);
        mloc[jj] = fmaxf(mloc[jj], sv);
      }
#pragma unroll
    for (int d = 1; d < 16; d <<= 1)
#pragma unroll
      for (int jj = 0; jj < 4; ++jj)
        mloc[jj] = fmaxf(mloc[jj], __shfl_xor(mloc[jj], d, 64));

    float corr[4];
#pragma unroll
    for (int jj = 0; jj < 4; ++jj) {
      float mn = fmaxf(m[jj], mloc[jj]);
      corr[jj] = __expf(m[jj] - mn);
      m[jj] = mn;
    }
#pragma unroll
    for (int fd = 0; fd < 4; ++fd)
#pragma unroll
      for (int jj = 0; jj < 4; ++jj) O[fd][jj] *= corr[jj];

    // ---- barrier B: retire V(kt) (44 younger: K4+mask8+stores32) ----
    asm volatile("s_waitcnt vmcnt(44)" ::: "memory");
    __builtin_amdgcn_s_barrier();
    __builtin_amdgcn_sched_barrier(0);

    // P + PV in 4 rounds of 32 kv (Ps per-wave [16][40])
    float psum[4] = {0.f, 0.f, 0.f, 0.f};
#pragma unroll
    for (int r = 0; r < 4; ++r) {
#pragma unroll
      for (int f2 = 0; f2 < 2; ++f2) {
        int f = r * 2 + f2;
#pragma unroll
        for (int jj = 0; jj < 4; ++jj) {
          float p = __expf(s[f][jj] - m[jj]);   // masked -> exp(~-1e20) = 0
          psum[jj] += p;
          Ps[w][(g * 4 + jj) * 40 + f2 * 16 + l15] = f2bf(p);
        }
      }
      bf16x8 pa = *(const bf16x8*)(&Ps[w][l15 * 40 + g * 8]);
#pragma unroll
      for (int fd = 0; fd < 4; ++fd) {
        int row = fd * 16 + l15;
        bf16x8 bv = *(const bf16x8*)(Vs + (row * 16 + ((r * 4 + g) ^ (row & 15))) * 8);
        O[fd] = MFMA(pa, bv, O[fd]);
      }
    }

#pragma unroll
    for (int d = 1; d < 16; d <<= 1)
#pragma unroll
      for (int jj = 0; jj < 4; ++jj)
        psum[jj] += __shfl_xor(psum[jj], d, 64);
#pragma unroll
    for (int jj = 0; jj < 4; ++jj) l[jj] = l[jj] * corr[jj] + psum[jj];
  }
  // epilogue: ctx[b][n][h*64+d] = O/l  (bf16)
  float inv[4];
#pragma unroll
  for (int jj = 0; jj < 4; ++jj) inv[jj] = 1.0f / l[jj];
  const int h = bh & 15;
#pragma unroll
  for (int fd = 0; fd < 4; ++fd)
#pragma unroll
    for (int jj = 0; jj < 4; ++jj) {
      int n = qt * 64 + w * 16 + g * 4 + jj;
      int c = h * 64 + fd * 16 + l15;
      ctx[((size_t)(b * 2048 + n)) * 1024 + c] = f2bf(O[fd][jj] * inv[jj]);
    }
}

extern "C" void kernel_launch(void* const* d_in, const int* in_sizes, int n_in,
                              void* d_out, int out_size, void* d_ws, size_t ws_size,
                              hipStream_t stream)
{
  const float* query = (const float*)d_in[0];
  const int*   mask  = (const int*)d_in[1];
  const float* wq = (const float*)d_in[2];
  const float* bq = (const float*)d_in[3];
  const float* wk = (const float*)d_in[4];
  const float* bk = (const float*)d_in[5];
  const float* wv = (const float*)d_in[6];
  const float* bv = (const float*)d_in[7];
  const float* wo = (const float*)d_in[8];
  const float* bo = (const float*)d_in[9];
  float* out = (float*)d_out;

  u16* ws   = (u16*)d_ws;
  u16* Ab   = ws;              // query bf16        [4096*1024]
  u16* Wqkv = ws + 4194304;    // wq/8, wk, wv      [3*1024*1024]
  u16* Wo   = ws + 7340032;    // wo                [1024*1024]
  u16* Qh   = ws + 8388608;    // [32][2048][64]
  u16* Kh   = ws + 12582912;   // [32][2048][64]
  u16* Vt   = ws + 16777216;   // [32][64][2048]  (written directly by qkv)
  u16* ctx  = ws + 20971520;   // [4096][1024]

  k_cast<<<4096, 256, 0, stream>>>(query, wq, wk, wv, wo, ws);
  k_gemm_qkv<<<768, 256, 0, stream>>>(Ab, Wqkv, bq, bk, bv, Qh, Kh, Vt);
  k_attn<<<1024, 256, 0, stream>>>(Qh, Kh, Vt, mask, out, ctx);
  k_gemm_out<<<256, 256, 0, stream>>>(ctx, Wo, bo, out);
}

// Round 18
// 200.487 us; speedup vs baseline: 1.0445x; 1.0445x over previous
//
#include <hip/hip_runtime.h>

typedef unsigned short u16;
typedef unsigned int u32;
typedef __attribute__((ext_vector_type(8))) __bf16 bf16x8;
typedef __attribute__((ext_vector_type(4))) float f32x4;

#define MFMA(a, b, c) __builtin_amdgcn_mfma_f32_16x16x32_bf16((a), (b), (c), 0, 0, 0)

__device__ __forceinline__ u16 f2bf(float f) {
  union { float f; unsigned u; } v; v.f = f;
  unsigned r = v.u + 0x7fffu + ((v.u >> 16) & 1u);
  return (u16)(r >> 16);
}

// async global->LDS, 16B per lane; LDS dest must be linear (base + lane*16)
__device__ __forceinline__ void gld16(const u16* g, u16* l) {
  __builtin_amdgcn_global_load_lds(
      (const __attribute__((address_space(1))) unsigned int*)(g),
      (__attribute__((address_space(3))) unsigned int*)(l), 16, 0, 0);
}

// ---------------- cast + prescale kernel ----------------
// dst layout (bf16 elems): [query 4M][wq/8 1M][wk 1M][wv 1M][wo 1M]
__global__ __launch_bounds__(256) void k_cast(
    const float* __restrict__ query, const float* __restrict__ wq,
    const float* __restrict__ wk, const float* __restrict__ wv,
    const float* __restrict__ wo, u16* __restrict__ dst)
{
  size_t i = ((size_t)blockIdx.x * 256 + threadIdx.x) * 8;
  const float* src; size_t off; float sc = 1.0f;
  if (i < 4194304u)      { src = query; off = i; }
  else if (i < 5242880u) { src = wq; off = i - 4194304u; sc = 0.125f; }
  else if (i < 6291456u) { src = wk; off = i - 5242880u; }
  else if (i < 7340032u) { src = wv; off = i - 6291456u; }
  else                   { src = wo; off = i - 7340032u; }
  float4 a = *(const float4*)(src + off);
  float4 b = *(const float4*)(src + off + 4);
  alignas(16) u16 r[8] = { f2bf(a.x*sc), f2bf(a.y*sc), f2bf(a.z*sc), f2bf(a.w*sc),
                           f2bf(b.x*sc), f2bf(b.y*sc), f2bf(b.z*sc), f2bf(b.w*sc) };
  *(int4*)(dst + i) = *(int4*)r;
}

// ---------------- QKV GEMM: [4096,1024] x [3072,1024]^T ----------------
// 128x128 tile, 4 waves (2x2). grid 768 = 24 n-tiles x 32 m-tiles, XCD-chunked.
// V panel is written DIRECTLY in transposed head layout Vt[bh][64][2048].
__global__ __launch_bounds__(256) void k_gemm_qkv(
    const u16* __restrict__ Ab, const u16* __restrict__ Wb,
    const float* __restrict__ bq, const float* __restrict__ bk, const float* __restrict__ bv,
    u16* __restrict__ Qh, u16* __restrict__ Kh, u16* __restrict__ Vt)
{
  const int fb = blockIdx.x;
  const int sb = (fb & 7) * 96 + (fb >> 3);     // 768/8 = 96 per XCD
  const int n0 = (sb % 24) * 128;
  const int m0 = (sb / 24) * 128;
  const int tid = threadIdx.x;
  const int w = tid >> 6, lane = tid & 63, g = lane >> 4, l15 = lane & 15;
  const int wm = w >> 1, wn = w & 1;
  __shared__ alignas(16) u16 As[128 * 32];
  __shared__ alignas(16) u16 Bs[128 * 32];
  f32x4 acc[4][4] = {};
  for (int k0 = 0; k0 < 1024; k0 += 32) {
    __syncthreads();
#pragma unroll
    for (int t = 0; t < 2; ++t) {
      int i = t * 256 + tid;
      int row = i >> 2, ch = i & 3, sch = ch ^ (row & 3);
      gld16(Ab + (size_t)(m0 + row) * 1024 + k0 + sch * 8, As + i * 8);
    }
#pragma unroll
    for (int t = 0; t < 2; ++t) {
      int i = t * 256 + tid;
      int row = i >> 2, ch = i & 3, sch = ch ^ (row & 3);
      gld16(Wb + (size_t)(n0 + row) * 1024 + k0 + sch * 8, Bs + i * 8);
    }
    __syncthreads();
    bf16x8 af[4], bfr[4];
#pragma unroll
    for (int i = 0; i < 4; ++i) {
      int row = wm * 64 + i * 16 + l15;
      af[i] = *(const bf16x8*)(As + (row * 4 + (g ^ (row & 3))) * 8);
    }
#pragma unroll
    for (int j = 0; j < 4; ++j) {
      int row = wn * 64 + j * 16 + l15;
      bfr[j] = *(const bf16x8*)(Bs + (row * 4 + (g ^ (row & 3))) * 8);
    }
#pragma unroll
    for (int i = 0; i < 4; ++i)
#pragma unroll
      for (int j = 0; j < 4; ++j)
        acc[i][j] = MFMA(af[i], bfr[j], acc[i][j]);
  }
  // epilogue: Q/K -> [bh][n][64]; V -> Vt[bh][64][2048] (transposed, fused)
  const int proj = n0 >> 10;                    // block-uniform (128 | 1024)
  const float* bias = (proj == 0) ? bq : (proj == 1) ? bk : bv;
  const float bsc = (proj == 0) ? 0.125f : 1.0f;
#pragma unroll
  for (int i = 0; i < 4; ++i)
#pragma unroll
    for (int j = 0; j < 4; ++j)
#pragma unroll
      for (int jj = 0; jj < 4; ++jj) {
        int mr = m0 + wm * 64 + i * 16 + g * 4 + jj;
        int c  = n0 + wn * 64 + j * 16 + l15;
        int d = c & 1023, h = d >> 6, d64 = d & 63;
        int b = mr >> 11, n = mr & 2047;
        int bh = (b << 4) | h;
        float v = acc[i][j][jj] + bias[d] * bsc;
        if (proj == 2) {
          Vt[((size_t)bh * 64 + d64) * 2048 + n] = f2bf(v);
        } else {
          u16* dst = (proj == 0) ? Qh : Kh;
          dst[((size_t)bh * 2048 + n) * 64 + d64] = f2bf(v);
        }
      }
}

// ---------------- out projection: ctx[4096,1024] x Wo[1024,1024]^T + bo ----------------
// grid 256 = 8 n-tiles x 32 m-tiles, XCD-chunked.
__global__ __launch_bounds__(256) void k_gemm_out(
    const u16* __restrict__ Ab, const u16* __restrict__ Wb,
    const float* __restrict__ bo, float* __restrict__ out)
{
  const int fb = blockIdx.x;
  const int sb = (fb & 7) * 32 + (fb >> 3);     // 256/8 = 32 per XCD
  const int n0 = (sb & 7) * 128;
  const int m0 = (sb >> 3) * 128;
  const int tid = threadIdx.x;
  const int w = tid >> 6, lane = tid & 63, g = lane >> 4, l15 = lane & 15;
  const int wm = w >> 1, wn = w & 1;
  __shared__ alignas(16) u16 As[128 * 32];
  __shared__ alignas(16) u16 Bs[128 * 32];
  f32x4 acc[4][4] = {};
  for (int k0 = 0; k0 < 1024; k0 += 32) {
    __syncthreads();
#pragma unroll
    for (int t = 0; t < 2; ++t) {
      int i = t * 256 + tid;
      int row = i >> 2, ch = i & 3, sch = ch ^ (row & 3);
      gld16(Ab + (size_t)(m0 + row) * 1024 + k0 + sch * 8, As + i * 8);
    }
#pragma unroll
    for (int t = 0; t < 2; ++t) {
      int i = t * 256 + tid;
      int row = i >> 2, ch = i & 3, sch = ch ^ (row & 3);
      gld16(Wb + (size_t)(n0 + row) * 1024 + k0 + sch * 8, Bs + i * 8);
    }
    __syncthreads();
    bf16x8 af[4], bfr[4];
#pragma unroll
    for (int i = 0; i < 4; ++i) {
      int row = wm * 64 + i * 16 + l15;
      af[i] = *(const bf16x8*)(As + (row * 4 + (g ^ (row & 3))) * 8);
    }
#pragma unroll
    for (int j = 0; j < 4; ++j) {
      int row = wn * 64 + j * 16 + l15;
      bfr[j] = *(const bf16x8*)(Bs + (row * 4 + (g ^ (row & 3))) * 8);
    }
#pragma unroll
    for (int i = 0; i < 4; ++i)
#pragma unroll
      for (int j = 0; j < 4; ++j)
        acc[i][j] = MFMA(af[i], bfr[j], acc[i][j]);
  }
#pragma unroll
  for (int i = 0; i < 4; ++i)
#pragma unroll
    for (int j = 0; j < 4; ++j)
#pragma unroll
      for (int jj = 0; jj < 4; ++jj) {
        int mr = m0 + wm * 64 + i * 16 + g * 4 + jj;
        int c  = n0 + wn * 64 + j * 16 + l15;
        out[(size_t)mr * 1024 + c] = acc[i][j][jj] + bo[c];
      }
}

// ---------------- fused flash attention + dot_prod write ----------------
// grid 1024 = 32 qtiles x 32 bh, XCD-chunked; block 256 = 4 waves.
// R15 (session best, 200.8us): K double-buffered, V single-buffered JIT,
// two COUNTED barriers/iter (A: vmcnt(40) retires K; B: vmcnt(44) retires V);
// NT S-stores never drained at barriers. LDS 53.0 KB -> 3 blocks/CU.
__global__ __launch_bounds__(256) void k_attn(
    const u16* __restrict__ Qh, const u16* __restrict__ Kh, const u16* __restrict__ Vt,
    const int* __restrict__ mask, float* __restrict__ dout, u16* __restrict__ ctx)
{
  const int fb = blockIdx.x;
  const int sb = (fb & 7) * 128 + (fb >> 3);    // 1024/8 = 128 per XCD
  const int qt = sb & 31;
  const int bh = sb >> 5;
  const int b  = bh >> 4;
  const int tid = threadIdx.x;
  const int w = tid >> 6, lane = tid & 63, g = lane >> 4, l15 = lane & 15;
  __shared__ alignas(16) u16 Ks[2][128 * 64];   // 32 KB (double-buffered)
  __shared__ alignas(16) u16 Vs[64 * 128];      // 16 KB (single, JIT)
  __shared__ alignas(16) u16 Ps[4][16 * 40];    // 5 KB, per-wave [q=16][kv=32]

  // Q fragments straight from global (once per block; k-chunks g and 4+g)
  const u16* Qrow = Qh + ((size_t)bh * 2048 + qt * 64 + w * 16 + l15) * 64;
  bf16x8 qf0 = *(const bf16x8*)(Qrow + g * 8);
  bf16x8 qf1 = *(const bf16x8*)(Qrow + 32 + g * 8);

  const u16* Kb = Kh + (size_t)bh * 131072;   // [2048][64]
  const u16* Vb = Vt + (size_t)bh * 131072;   // [64][2048]

  auto stageK = [&](int buf, int kt) {        // 4 gld16 / lane
#pragma unroll
    for (int it = 0; it < 4; ++it) {
      int i = it * 256 + tid;
      int row = i >> 3, ch = i & 7, sch = ch ^ (row & 7);
      gld16(Kb + (size_t)(kt * 128 + row) * 64 + sch * 8, &Ks[buf][i * 8]);
    }
  };
  auto stageV = [&](int kt) {                 // 4 gld16 / lane
#pragma unroll
    for (int it = 0; it < 4; ++it) {
      int i = it * 256 + tid;
      int row = i >> 4, ch = i & 15, sch = ch ^ (row & 15);
      gld16(Vb + (size_t)row * 2048 + kt * 128 + sch * 8, &Vs[i * 8]);
    }
  };

  stageK(0, 0);
  asm volatile("s_waitcnt vmcnt(0)" ::: "memory");
  __builtin_amdgcn_s_barrier();
  __builtin_amdgcn_sched_barrier(0);

  float m[4] = {-3e38f, -3e38f, -3e38f, -3e38f};
  float l[4] = {0.f, 0.f, 0.f, 0.f};
  f32x4 O[4] = {};
  const int* maskb = mask + b * 2048;
  float* Sbase = dout + 4194304 + (size_t)bh * 4194304
               + (size_t)(qt * 64 + w * 16 + g * 4) * 2048 + l15;

  for (int kt = 0; kt < 16; ++kt) {
    const int cur = kt & 1;
    // ---- barrier A: all waves done PV(kt-1); retire K(kt); stores stay ----
    asm volatile("s_waitcnt vmcnt(40)" ::: "memory");
    __builtin_amdgcn_s_barrier();
    __builtin_amdgcn_sched_barrier(0);

    stageV(kt);                               // V just-in-time (oldest this iter)
    __builtin_amdgcn_sched_barrier(0);
    stageK(cur ^ 1, (kt + 1) & 15);           // K prefetch (wraps at kt=15)
    __builtin_amdgcn_sched_barrier(0);

    int mk[8];
#pragma unroll
    for (int f = 0; f < 8; ++f) mk[f] = maskb[kt * 128 + f * 16 + l15];

    // S = Q K^T  (wave's 16 q-rows x 128 kv)
    f32x4 s[8];
#pragma unroll
    for (int f = 0; f < 8; ++f) {
      int row = f * 16 + l15;
      bf16x8 kf0 = *(const bf16x8*)(&Ks[cur][(row * 8 + ((0 + g) ^ (row & 7))) * 8]);
      bf16x8 kf1 = *(const bf16x8*)(&Ks[cur][(row * 8 + ((4 + g) ^ (row & 7))) * 8]);
      f32x4 t = {};
      t = MFMA(qf0, kf0, t);
      t = MFMA(qf1, kf1, t);
      s[f] = t;
    }

    float fb8[8];
#pragma unroll
    for (int f = 0; f < 8; ++f) fb8[f] = (mk[f] != 0) ? 0.f : -1e20f;

    // biased S: NT store + unconditional max
    float mloc[4] = {-3e38f, -3e38f, -3e38f, -3e38f};
#pragma unroll
    for (int jj = 0; jj < 4; ++jj)
#pragma unroll
      for (int f = 0; f < 8; ++f) {
        float sv = s[f][jj] + fb8[f];
        s[f][jj] = sv;
        __builtin_nontemporal_store(sv, &Sbase[(size_t)jj * 2048 + kt * 128 + f * 16]);
        mloc[jj] = fmaxf(mloc[jj], sv);
      }
#pragma unroll
    for (int d = 1; d < 16; d <<= 1)
#pragma unroll
      for (int jj = 0; jj < 4; ++jj)
        mloc[jj] = fmaxf(mloc[jj], __shfl_xor(mloc[jj], d, 64));

    float corr[4];
#pragma unroll
    for (int jj = 0; jj < 4; ++jj) {
      float mn = fmaxf(m[jj], mloc[jj]);
      corr[jj] = __expf(m[jj] - mn);
      m[jj] = mn;
    }
#pragma unroll
    for (int fd = 0; fd < 4; ++fd)
#pragma unroll
      for (int jj = 0; jj < 4; ++jj) O[fd][jj] *= corr[jj];

    // ---- barrier B: retire V(kt) (44 younger: K4+mask8+stores32) ----
    asm volatile("s_waitcnt vmcnt(44)" ::: "memory");
    __builtin_amdgcn_s_barrier();
    __builtin_amdgcn_sched_barrier(0);

    // P + PV in 4 rounds of 32 kv (Ps per-wave [16][40])
    float psum[4] = {0.f, 0.f, 0.f, 0.f};
#pragma unroll
    for (int r = 0; r < 4; ++r) {
#pragma unroll
      for (int f2 = 0; f2 < 2; ++f2) {
        int f = r * 2 + f2;
#pragma unroll
        for (int jj = 0; jj < 4; ++jj) {
          float p = __expf(s[f][jj] - m[jj]);   // masked -> exp(~-1e20) = 0
          psum[jj] += p;
          Ps[w][(g * 4 + jj) * 40 + f2 * 16 + l15] = f2bf(p);
        }
      }
      bf16x8 pa = *(const bf16x8*)(&Ps[w][l15 * 40 + g * 8]);
#pragma unroll
      for (int fd = 0; fd < 4; ++fd) {
        int row = fd * 16 + l15;
        bf16x8 bv = *(const bf16x8*)(Vs + (row * 16 + ((r * 4 + g) ^ (row & 15))) * 8);
        O[fd] = MFMA(pa, bv, O[fd]);
      }
    }

#pragma unroll
    for (int d = 1; d < 16; d <<= 1)
#pragma unroll
      for (int jj = 0; jj < 4; ++jj)
        psum[jj] += __shfl_xor(psum[jj], d, 64);
#pragma unroll
    for (int jj = 0; jj < 4; ++jj) l[jj] = l[jj] * corr[jj] + psum[jj];
  }
  // epilogue: ctx[b][n][h*64+d] = O/l  (bf16)
  float inv[4];
#pragma unroll
  for (int jj = 0; jj < 4; ++jj) inv[jj] = 1.0f / l[jj];
  const int h = bh & 15;
#pragma unroll
  for (int fd = 0; fd < 4; ++fd)
#pragma unroll
    for (int jj = 0; jj < 4; ++jj) {
      int n = qt * 64 + w * 16 + g * 4 + jj;
      int c = h * 64 + fd * 16 + l15;
      ctx[((size_t)(b * 2048 + n)) * 1024 + c] = f2bf(O[fd][jj] * inv[jj]);
    }
}

extern "C" void kernel_launch(void* const* d_in, const int* in_sizes, int n_in,
                              void* d_out, int out_size, void* d_ws, size_t ws_size,
                              hipStream_t stream)
{
  const float* query = (const float*)d_in[0];
  const int*   mask  = (const int*)d_in[1];
  const float* wq = (const float*)d_in[2];
  const float* bq = (const float*)d_in[3];
  const float* wk = (const float*)d_in[4];
  const float* bk = (const float*)d_in[5];
  const float* wv = (const float*)d_in[6];
  const float* bv = (const float*)d_in[7];
  const float* wo = (const float*)d_in[8];
  const float* bo = (const float*)d_in[9];
  float* out = (float*)d_out;

  u16* ws   = (u16*)d_ws;
  u16* Ab   = ws;              // query bf16        [4096*1024]
  u16* Wqkv = ws + 4194304;    // wq/8, wk, wv      [3*1024*1024]
  u16* Wo   = ws + 7340032;    // wo                [1024*1024]
  u16* Qh   = ws + 8388608;    // [32][2048][64]
  u16* Kh   = ws + 12582912;   // [32][2048][64]
  u16* Vt   = ws + 16777216;   // [32][64][2048]  (written directly by qkv)
  u16* ctx  = ws + 20971520;   // [4096][1024]

  k_cast<<<4096, 256, 0, stream>>>(query, wq, wk, wv, wo, ws);
  k_gemm_qkv<<<768, 256, 0, stream>>>(Ab, Wqkv, bq, bk, bv, Qh, Kh, Vt);
  k_attn<<<1024, 256, 0, stream>>>(Qh, Kh, Vt, mask, out, ctx);
  k_gemm_out<<<256, 256, 0, stream>>>(ctx, Wo, bo, out);
}